// Round 13
// baseline (1053.544 us; speedup 1.0000x reference)
//
#include <hip/hip_runtime.h>
#include <math.h>

#define Sv 21952
#define HWc 784
#define CNT 351232.0f
#define EPS 1e-5f
#define PV 27000              // 30^3 padded volume per image
#define PT (16 * PV)          // padded positions total

typedef short bf16x8 __attribute__((ext_vector_type(8)));
typedef float f32x4 __attribute__((ext_vector_type(4)));
typedef float f32x16 __attribute__((ext_vector_type(16)));
typedef unsigned short u16x8 __attribute__((ext_vector_type(8)));

__device__ __forceinline__ unsigned short f2bf(float f) {
    unsigned u = __float_as_uint(f);
    u = (u + 0x7FFFu + ((u >> 16) & 1u)) >> 16;
    return (unsigned short)u;
}
__device__ __forceinline__ float bf2f(unsigned short h) {
    return __uint_as_float(((unsigned)h) << 16);
}

// async global->LDS DMA, 16B per lane. LDS dest = wave-uniform base + lane*16.
__device__ __forceinline__ void async16(const unsigned short* g, unsigned short* l) {
    __builtin_amdgcn_global_load_lds(
        (const __attribute__((address_space(1))) unsigned int*)g,
        (__attribute__((address_space(3))) unsigned int*)l, 16, 0, 0);
}

// ---------------------------------------------- border-only zero of padded bufs
// Producers write the full interior (z,y,x in 1..28) every call; only borders
// must be zero for halo reads. 36MB of writes replaces 193MB of memsets.
template<int C>
__global__ __launch_bounds__(256) void k_zborder(unsigned short* __restrict__ buf) {
    int idx = blockIdx.x * 256 + threadIdx.x;
    if (idx >= PT) return;
    int p = idx % PV;
    int z = p / 900, y = (p / 30) % 30, x = p % 30;
    if (z >= 1 && z <= 28 && y >= 1 && y <= 28 && x >= 1 && x <= 28) return;
    u16x8 zv = {0, 0, 0, 0, 0, 0, 0, 0};
    u16x8* dst = (u16x8*)(buf + (long)idx * C);
    #pragma unroll
    for (int q = 0; q < C / 8; q++) dst[q] = zv;
}

// ---------------------------------------------------------------- offsets conv
// Weights/bias read directly from global with wave-uniform indices -> compiler
// emits scalar s_load (constant cache) + v_fmac with SGPR operand, eliminating
// the ~2187 per-thread ds_read_b32 of the LDS-staged version.
__global__ __launch_bounds__(256) void k_offsets(const float* __restrict__ x,
        const float* __restrict__ ow, const float* __restrict__ ob,
        float* __restrict__ out) {
    int idx = blockIdx.x * 256 + threadIdx.x;
    int n = idx / Sv, s = idx % Sv;
    int d = s / HWc, r = s % HWc, h = r / 28, w = r % 28;
    const float* xb = x + (long)n * Sv;
    float xv[27];
    #pragma unroll
    for (int dz = 0; dz < 3; dz++)
      #pragma unroll
      for (int dy = 0; dy < 3; dy++)
        #pragma unroll
        for (int dx = 0; dx < 3; dx++) {
            int zz = d + dz - 1, yy = h + dy - 1, xx = w + dx - 1;
            bool ok = (unsigned)zz < 28u && (unsigned)yy < 28u && (unsigned)xx < 28u;
            xv[dz * 9 + dy * 3 + dx] = ok ? xb[zz * HWc + yy * 28 + xx] : 0.f;
        }
    float* op = out + (long)n * 81 * Sv + s;
    for (int c = 0; c < 81; c++) {
        float acc = ob[c];
        #pragma unroll
        for (int k = 0; k < 27; k++) acc += xv[k] * ow[c * 27 + k];
        op[(long)c * Sv] = acc;
    }
}

// ---------------------------------------------------------------- deform conv
// r12-verbatim (proven; r11 showed this latency-bound gather kernel is
// hypersensitive to register/atomic perturbation — do not touch blind).
__device__ __forceinline__ float fetch_pad(const float* __restrict__ xb,
                                           int zq, int yq, int xq) {
    int z = zq - 1, y = yq - 1, xx = xq - 1;
    bool ok = (unsigned)z < 28u && (unsigned)y < 28u && (unsigned)xx < 28u;
    return ok ? xb[z * HWc + y * 28 + xx] : 0.f;
}

__global__ __launch_bounds__(256) void k_deform(const float* __restrict__ x,
        const float* __restrict__ off, const float* __restrict__ dw,
        unsigned short* __restrict__ h1p) {
    __shared__ float w_s[32 * 27];
    for (int i = threadIdx.x; i < 32 * 27; i += 256) w_s[i] = dw[i];
    __syncthreads();
    int idx = blockIdx.x * 256 + threadIdx.x;
    int n = idx / Sv, s = idx % Sv;
    int d = s / HWc, r = s % HWc, h = r / 28, w = r % 28;
    const float* xb = x + (long)n * Sv;
    const float* ofb = off + (long)n * 81 * Sv + s;
    float v[27];
    #pragma unroll
    for (int k = 0; k < 27; k++) {
        int ki = k / 9, kj = (k / 3) % 3, kl = k % 3;
        float pd = (float)(d + ki) + ofb[(long)k * Sv];
        float ph = (float)(h + kj) + ofb[(long)(27 + k) * Sv];
        float pw = (float)(w + kl) + ofb[(long)(54 + k) * Sv];
        float q0d = floorf(pd), q0h = floorf(ph), q0w = floorf(pw);
        float pcd = fminf(fmaxf(pd, 0.f), 29.f);
        float pch = fminf(fmaxf(ph, 0.f), 29.f);
        float pcw = fminf(fmaxf(pw, 0.f), 29.f);
        float q0cd = fminf(fmaxf(q0d, 0.f), 29.f);
        float q0ch = fminf(fmaxf(q0h, 0.f), 29.f);
        float q0cw = fminf(fmaxf(q0w, 0.f), 29.f);
        float q1cd = fminf(fmaxf(q0d + 1.f, 0.f), 29.f);
        float q1ch = fminf(fmaxf(q0h + 1.f, 0.f), 29.f);
        float q1cw = fminf(fmaxf(q0w + 1.f, 0.f), 29.f);
        float wz[2] = {1.f + (q0cd - pcd), 1.f - (q1cd - pcd)};
        float wy[2] = {1.f + (q0ch - pch), 1.f - (q1ch - pch)};
        float wx[2] = {1.f + (q0cw - pcw), 1.f - (q1cw - pcw)};
        int qz[2] = {(int)q0cd, (int)q1cd};
        int qy[2] = {(int)q0ch, (int)q1ch};
        int qx[2] = {(int)q0cw, (int)q1cw};
        float val = 0.f;
        #pragma unroll
        for (int cz = 0; cz < 2; cz++)
          #pragma unroll
          for (int cy = 0; cy < 2; cy++)
            #pragma unroll
            for (int cx = 0; cx < 2; cx++)
                val += wz[cz] * wy[cy] * wx[cx] * fetch_pad(xb, qz[cz], qy[cy], qx[cx]);
        v[k] = val;
    }
    unsigned pb = ((((unsigned)n * 30 + (d + 1)) * 30 + (h + 1)) * 30 + (w + 1)) * 32;
    unsigned short tmp[32];
    #pragma unroll
    for (int o = 0; o < 32; o++) {
        float acc = 0.f;
        #pragma unroll
        for (int k = 0; k < 27; k++) acc += v[k] * w_s[o * 27 + k];
        tmp[o] = f2bf(fmaxf(acc, 0.f));
    }
    u16x8* dst = (u16x8*)(h1p + pb);
    #pragma unroll
    for (int q = 0; q < 4; q++) dst[q] = ((u16x8*)tmp)[q];
}

// ------------------------------------------------- BN1 stats over padded h1p
template<int C>
__global__ __launch_bounds__(256) void k_stats_p(const unsigned short* __restrict__ buf,
        float* __restrict__ sums) {
    constexpr int G = C / 8;
    constexpr int P = 256 / G;
    int t = threadIdx.x;
    int oct = t % G, ps = t / G;
    float s1[8], s2[8];
    #pragma unroll
    for (int j = 0; j < 8; j++) { s1[j] = 0.f; s2[j] = 0.f; }
    for (int p = blockIdx.x * P + ps; p < PT; p += gridDim.x * P) {
        u16x8 v = *(const u16x8*)(buf + (long)p * C + oct * 8);
        #pragma unroll
        for (int j = 0; j < 8; j++) {
            float f = bf2f(v[j]);
            s1[j] += f; s2[j] += f * f;
        }
    }
    __shared__ float sh[2][C];
    if (t < C) { sh[0][t] = 0.f; sh[1][t] = 0.f; }
    __syncthreads();
    #pragma unroll
    for (int j = 0; j < 8; j++) {
        atomicAdd(&sh[0][oct * 8 + j], s1[j]);
        atomicAdd(&sh[1][oct * 8 + j], s2[j]);
    }
    __syncthreads();
    if (t < C) { atomicAdd(&sums[t], sh[0][t]); atomicAdd(&sums[C + t], sh[1][t]); }
}

__global__ void k_finalize(const float* __restrict__ sums, const float* __restrict__ g,
        const float* __restrict__ bb, float* __restrict__ aff, int C) {
    int c = threadIdx.x;
    if (c < C) {
        float mean = sums[c] * (1.f / CNT);
        float var = sums[C + c] * (1.f / CNT) - mean * mean;
        float a = g[c] * rsqrtf(var + EPS);
        aff[c] = a;
        aff[C + c] = bb[c] - mean * a;
    }
}

// ------------------- weight prep: B-fragment swizzle for 32x32x16 MFMA
template<int CI, int COT>
__global__ __launch_bounds__(256) void k_wfrag32(const float* __restrict__ w,
        const float* __restrict__ affa, unsigned short* __restrict__ wf) {
    constexpr int NT32 = COT / 32;
    constexpr int KC = CI / 32;
    int tid = blockIdx.x * 256 + threadIdx.x;
    int lane = tid & 63, rest = tid >> 6;
    int kh = rest & 1; rest >>= 1;
    int nt = rest % NT32; rest /= NT32;
    int kc = rest % KC;
    int tap = rest / KC;
    if (tap >= 27) return;
    int co = nt * 32 + (lane & 31);
    int hi = lane >> 5;
    unsigned short tmp[8];
    #pragma unroll
    for (int j = 0; j < 8; j++) {
        int ci = kc * 32 + kh * 16 + hi * 8 + j;
        tmp[j] = f2bf(w[((long)co * CI + ci) * 27 + tap] * affa[ci]);
    }
    long oidx = ((((long)kc * 27 + tap) * NT32 + nt) * 2 + kh) * 512 + lane * 8;
    *(u16x8*)(wf + oidx) = *(u16x8*)tmp;
}

// --------------------- border-bias table, stage 1: per-tap channel sums
template<int CI, int COT>
__global__ __launch_bounds__(256) void k_tapsum(const float* __restrict__ w,
        const float* __restrict__ affb, float* __restrict__ S) {
    __shared__ float acc[27];
    int co = blockIdx.x;
    int t = threadIdx.x;
    if (t < 27) acc[t] = 0.f;
    __syncthreads();
    const float* wr = w + (long)co * CI * 27;
    for (int idx = t; idx < CI * 27; idx += 256)
        atomicAdd(&acc[idx % 27], wr[idx] * affb[idx / 27]);
    __syncthreads();
    if (t < 27) S[t * COT + co] = acc[t];
}

// --------------------- border-bias table, stage 2: combine valid taps per class
template<int COT>
__global__ void k_btab2(const float* __restrict__ S, const float* __restrict__ bias,
        float* __restrict__ T) {
    int tid = blockIdx.x * 256 + threadIdx.x;
    if (tid >= 27 * COT) return;
    int co = tid % COT, cls = tid / COT;
    int xc = cls % 3, yc = (cls / 3) % 3, zc = cls / 9;
    float val = bias[co];
    #pragma unroll
    for (int t = 0; t < 27; t++) {
        int dx = t % 3, dy = (t / 3) % 3, dz = t / 9;
        bool ok = (zc == 1 || (zc == 0 && dz >= 1) || (zc == 2 && dz <= 1))
               && (yc == 1 || (yc == 0 && dy >= 1) || (yc == 2 && dy <= 1))
               && (xc == 1 || (xc == 0 && dx >= 1) || (xc == 2 && dx <= 1));
        if (ok) val += S[t * COT + co];
    }
    T[cls * COT + co] = val;
}

// ------------------------------------------------------ MFMA implicit-GEMM conv
// 32x32x16 MFMA, M=256 block tile, 4 waves, wave tile M=128 x N=(COT/2).
// Stride-80 LDS (conflict-free), global_load_lds staging, B tap-dbuf.
// Fused BN stats in epilogue. SMODE 0: write out + sums. SMODE 1 (conv4):
// no output write + pooled[n]/chsq.
template<int CI, int COT, int WN, bool PAD_OUT, int SMODE>
__global__ __launch_bounds__(WN * 128, 2) void k_conv_mfma(
        const unsigned short* __restrict__ in,
        const unsigned short* __restrict__ wfrag,
        const float* __restrict__ Ttab,
        unsigned short* __restrict__ out,
        float* __restrict__ sa, float* __restrict__ sb) {
    constexpr int KC = CI / 32;
    constexpr int NT32 = COT / 32;
    constexpr int NTW = NT32 / 2;         // nt tiles per wave (4 waves)
    constexpr int NT = WN * 128;
    constexpr int CP = 720;               // 4z * 6y * 30x halo positions
    constexpr int CUU = CP * 5;           // 3600 16B units (5/pos, stride-80)
    constexpr int NLOAD = (CUU + NT - 1) / NT;
    constexpr int LDSU = CUU + 48;        // pad for last partial wave
    __shared__ unsigned short lds[LDSU * 8];   // 58368 B
    __shared__ float shs[2][COT];

    int tid = threadIdx.x, wv = tid >> 6, lane = tid & 63;
    int lcol = lane & 31, hi = lane >> 5;
    int wv_m = wv & 1, wv_n = wv >> 1;
    if (tid < COT) { shs[0][tid] = 0.f; shs[1][tid] = 0.f; }

    // XCD swizzle: each XCD (bx%8) owns 2 images; grid 1568 = 8*196
    int bx = blockIdx.x;
    int xcd = bx & 7, loc = bx >> 3;
    int n = xcd * 2 + loc / 98;
    int rem = loc % 98;
    int z0 = (rem / 7) * 2;               // even z-tile base, 0..26
    int y0 = (rem % 7) * 4;
    const unsigned short* src = in + ((long)((n * 30 + z0) * 30 + y0) * 30) * CI;

    // per-lane A bases (bytes into lds). wave wv_m owns rows wv_m*128..+127.
    int baseA[4];
    #pragma unroll
    for (int mt = 0; mt < 4; mt++) {
        int x = lcol; if (x > 27) x = 27;         // clip lanes (rows masked at store)
        int pos = (wv_m * 6 + mt) * 30 + x;
        baseA[mt] = pos * 80 + hi * 16;
    }

    f32x16 acc[4][NTW];
    #pragma unroll
    for (int mt = 0; mt < 4; mt++)
        #pragma unroll
        for (int nt = 0; nt < NTW; nt++)
            #pragma unroll
            for (int e = 0; e < 16; e++) acc[mt][nt][e] = 0.f;

    for (int kc = 0; kc < KC; kc++) {
        if (kc) __syncthreads();                  // all waves done reading lds
        #pragma unroll
        for (int j = 0; j < NLOAD; j++) {
            int wb = j * NT + (wv << 6);          // wave-uniform dest base (16B units)
            if (wb < CUU) {
                int u = wb + lane;
                if (u >= CUU) u = CUU - 1;        // clamp source (dest in pad region)
                int p = u / 5, s = u - p * 5;     // 5 units per position
                int q = s & 3;                    // pad slot s==4 dups quad 0
                int zl = p / 180, r = p - zl * 180;
                int yl = r / 30, xl = r - yl * 30;
                int so = (zl * 900 + yl * 30 + xl) * CI + q * 8 + kc * 32;
                async16(src + so, lds + (wb << 3));
            }
        }
        __syncthreads();                          // vmcnt(0) drain -> chunk staged
        const unsigned short* pwk =
            wfrag + (long)(kc * 27) * NT32 * 1024 + (long)wv_n * (NTW * 1024)
                  + lane * 8;
        bf16x8 bc[NTW][2];
        #pragma unroll
        for (int nt = 0; nt < NTW; nt++)
            #pragma unroll
            for (int kh = 0; kh < 2; kh++)
                bc[nt][kh] = *(const bf16x8*)(pwk + nt * 1024 + kh * 512);
        #pragma unroll
        for (int tap = 0; tap < 27; tap++) {
            int td = (((tap / 9) * 6 + (tap % 9) / 3) * 30 + tap % 3) * 80;
            bf16x8 bn[NTW][2];
            if (tap < 26) {                       // prefetch next tap's B
                const unsigned short* pwn = pwk + (long)(tap + 1) * NT32 * 1024;
                #pragma unroll
                for (int nt = 0; nt < NTW; nt++)
                    #pragma unroll
                    for (int kh = 0; kh < 2; kh++)
                        bn[nt][kh] = *(const bf16x8*)(pwn + nt * 1024 + kh * 512);
            }
            bf16x8 a[2][4];
            #pragma unroll
            for (int kh = 0; kh < 2; kh++)
                #pragma unroll
                for (int mt = 0; mt < 4; mt++)
                    a[kh][mt] = *(const bf16x8*)((const char*)lds
                                 + baseA[mt] + td + kh * 32);
            #pragma unroll
            for (int kh = 0; kh < 2; kh++)
                #pragma unroll
                for (int mt = 0; mt < 4; mt++)
                    #pragma unroll
                    for (int nt = 0; nt < NTW; nt++)
                        acc[mt][nt] = __builtin_amdgcn_mfma_f32_32x32x16_bf16(
                            a[kh][mt], bc[nt][kh], acc[mt][nt], 0, 0, 0);
            if (tap < 26) {
                #pragma unroll
                for (int nt = 0; nt < NTW; nt++)
                    #pragma unroll
                    for (int kh = 0; kh < 2; kh++)
                        bc[nt][kh] = bn[nt][kh];
            }
        }
    }

    // ---- epilogue: C/D layout col=lane&31, row=(reg&3)+8*(reg>>2)+4*(lane>>5)
    int zz = z0 + wv_m;
    int zc = (zz == 0) ? 0 : ((zz == 27) ? 2 : 1);
    float s1a[NTW], s2a[NTW];
    #pragma unroll
    for (int nt = 0; nt < NTW; nt++) { s1a[nt] = 0.f; s2a[nt] = 0.f; }
    #pragma unroll
    for (int mt = 0; mt < 4; mt++) {
        int y = y0 + mt;
        int yc = (y == 0) ? 0 : ((y == 27) ? 2 : 1);
        #pragma unroll
        for (int reg = 0; reg < 16; reg++) {
            int x = (reg & 3) + 8 * (reg >> 2) + 4 * hi;
            if (x >= 28) continue;                // per-lane predicate (hi half)
            int xc = (x == 0) ? 0 : ((x == 27) ? 2 : 1);
            int cls = (zc * 3 + yc) * 3 + xc;
            long ob = 0;
            if constexpr (SMODE == 0) {
                if (PAD_OUT)
                    ob = ((long)((n * 30 + zz + 1) * 30 + y + 1) * 30 + x + 1) * COT;
                else
                    ob = ((long)n * Sv + zz * HWc + y * 28 + x) * COT;
            }
            #pragma unroll
            for (int nt = 0; nt < NTW; nt++) {
                int co = wv_n * (NTW * 32) + nt * 32 + lcol;
                float v = acc[mt][nt][reg] + Ttab[cls * COT + co];
                unsigned short hb = f2bf(fmaxf(v, 0.f));
                if constexpr (SMODE == 0) out[ob + co] = hb;
                float vr = bf2f(hb);
                s1a[nt] += vr;
                s2a[nt] += vr * vr;
            }
        }
    }
    #pragma unroll
    for (int nt = 0; nt < NTW; nt++) {
        int co = wv_n * (NTW * 32) + nt * 32 + lcol;
        atomicAdd(&shs[0][co], s1a[nt]);
        atomicAdd(&shs[1][co], s2a[nt]);
    }
    __syncthreads();
    if (tid < COT) {
        if constexpr (SMODE == 1) {
            atomicAdd(&sa[n * COT + tid], shs[0][tid]);
        } else {
            atomicAdd(&sa[tid], shs[0][tid]);
        }
        atomicAdd(&sb[tid], shs[1][tid]);
    }
}

// -------------------------------------------------------------------- head
__global__ __launch_bounds__(256) void k_head(const float* __restrict__ pooled,
        const float* __restrict__ chsq, const float* __restrict__ g4,
        const float* __restrict__ b4, const float* __restrict__ fcw,
        const float* __restrict__ fcb, float* __restrict__ out) {
    __shared__ float feat[16 * 128];
    __shared__ float lg[160];
    __shared__ float corr[16];
    int t = threadIdx.x;
    if (t < 128) {
        float sum = 0.f;
        for (int n = 0; n < 16; n++) sum += pooled[n * 128 + t];
        float mean = sum * (1.f / CNT);
        float var = chsq[t] * (1.f / CNT) - mean * mean;
        float a = g4[t] * rsqrtf(var + EPS);
        float bb = b4[t] - mean * a;
        for (int n = 0; n < 16; n++)
            feat[n * 128 + t] = a * (pooled[n * 128 + t] * (1.f / (float)Sv)) + bb;
    }
    __syncthreads();
    if (t < 160) {
        int n = t / 10, j = t % 10;
        float acc = fcb[j];
        for (int c = 0; c < 128; c++) acc += feat[n * 128 + c] * fcw[j * 128 + c];
        lg[t] = acc;
    }
    __syncthreads();
    if (t < 16) {
        float mx = -1e30f;
        for (int j = 0; j < 10; j++) mx = fmaxf(mx, lg[t * 10 + j]);
        float se = 0.f;
        for (int j = 0; j < 10; j++) se += expf(lg[t * 10 + j] - mx);
        corr[t] = mx + logf(se);
    }
    __syncthreads();
    if (t < 160) out[t] = lg[t] - corr[t / 10];
}

// -------------------------------------------------------------------- launch
#define OFF_H3P 0L
#define OFF_H2P 110592000L
#define OFF_H1P 165888000L
#define OFF_WF2 200507392L
#define OFF_WF3 200617984L
#define OFF_WF4 201060352L
#define OFF_STATS 201945088L

extern "C" void kernel_launch(void* const* d_in, const int* in_sizes, int n_in,
                              void* d_out, int out_size, void* d_ws, size_t ws_size,
                              hipStream_t stream) {
    const float* x       = (const float*)d_in[0];
    const float* off_w   = (const float*)d_in[1];
    const float* off_b   = (const float*)d_in[2];
    const float* dconv_w = (const float*)d_in[3];
    const float* bn1_g   = (const float*)d_in[4];
    const float* bn1_b   = (const float*)d_in[5];
    const float* conv2_w = (const float*)d_in[6];
    const float* conv2_b = (const float*)d_in[7];
    const float* bn2_g   = (const float*)d_in[8];
    const float* bn2_b   = (const float*)d_in[9];
    const float* conv3_w = (const float*)d_in[10];
    const float* conv3_b = (const float*)d_in[11];
    const float* bn3_g   = (const float*)d_in[12];
    const float* bn3_b   = (const float*)d_in[13];
    const float* conv4_w = (const float*)d_in[14];
    const float* conv4_b = (const float*)d_in[15];
    const float* bn4_g   = (const float*)d_in[16];
    const float* bn4_b   = (const float*)d_in[17];
    const float* fc_w    = (const float*)d_in[18];
    const float* fc_b    = (const float*)d_in[19];

    float* out = (float*)d_out;
    float* offsets = out + 160;

    char* ws = (char*)d_ws;
    unsigned short* h3p = (unsigned short*)(ws + OFF_H3P);
    unsigned short* h2p = (unsigned short*)(ws + OFF_H2P);
    unsigned short* h1p = (unsigned short*)(ws + OFF_H1P);
    unsigned short* wf2 = (unsigned short*)(ws + OFF_WF2);
    unsigned short* wf3 = (unsigned short*)(ws + OFF_WF3);
    unsigned short* wf4 = (unsigned short*)(ws + OFF_WF4);
    float* st = (float*)(ws + OFF_STATS);
    float* sums1 = st;        float* aff1 = st + 64;
    float* sums2 = st + 128;  float* aff2 = st + 256;
    float* sums3 = st + 384;  float* aff3 = st + 640;
    float* chsq4 = st + 896;  float* pooled = st + 1024;
    float* T2 = st + 4096;    float* T3 = st + 8192;   float* T4 = st + 16384;
    float* Sb = st + 20480;   // 27*COT per-tap sums scratch (<= 3456 floats)

    hipMemsetAsync(st, 0, 3072 * sizeof(float), stream);
    k_zborder<32><<<dim3(1688), 256, 0, stream>>>(h1p);
    k_zborder<64><<<dim3(1688), 256, 0, stream>>>(h2p);
    k_zborder<128><<<dim3(1688), 256, 0, stream>>>(h3p);

    k_offsets<<<dim3(1372), 256, 0, stream>>>(x, off_w, off_b, offsets);
    k_deform<<<dim3(1372), 256, 0, stream>>>(x, offsets, dconv_w, h1p);

    k_stats_p<32><<<dim3(432), 256, 0, stream>>>(h1p, sums1);
    k_finalize<<<1, 32, 0, stream>>>(sums1, bn1_g, bn1_b, aff1, 32);
    k_wfrag32<32, 64><<<dim3(27), 256, 0, stream>>>(conv2_w, aff1, wf2);
    k_tapsum<32, 64><<<dim3(64), 256, 0, stream>>>(conv2_w, aff1 + 32, Sb);
    k_btab2<64><<<dim3(7), 256, 0, stream>>>(Sb, conv2_b, T2);
    k_conv_mfma<32, 64, 2, true, 0><<<dim3(1568), 256, 0, stream>>>(
        h1p, wf2, T2, h2p, sums2, sums2 + 64);

    k_finalize<<<1, 64, 0, stream>>>(sums2, bn2_g, bn2_b, aff2, 64);
    k_wfrag32<64, 128><<<dim3(108), 256, 0, stream>>>(conv3_w, aff2, wf3);
    k_tapsum<64, 128><<<dim3(128), 256, 0, stream>>>(conv3_w, aff2 + 64, Sb);
    k_btab2<128><<<dim3(14), 256, 0, stream>>>(Sb, conv3_b, T3);
    k_conv_mfma<64, 128, 2, true, 0><<<dim3(1568), 256, 0, stream>>>(
        h2p, wf3, T3, h3p, sums3, sums3 + 128);

    k_finalize<<<1, 128, 0, stream>>>(sums3, bn3_g, bn3_b, aff3, 128);
    k_wfrag32<128, 128><<<dim3(216), 256, 0, stream>>>(conv4_w, aff3, wf4);
    k_tapsum<128, 128><<<dim3(128), 256, 0, stream>>>(conv4_w, aff3 + 128, Sb);
    k_btab2<128><<<dim3(14), 256, 0, stream>>>(Sb, conv4_b, T4);
    k_conv_mfma<128, 128, 2, false, 1><<<dim3(1568), 256, 0, stream>>>(
        h3p, wf4, T4, (unsigned short*)0, pooled, chsq4);

    k_head<<<1, 256, 0, stream>>>(pooled, chsq4, bn4_g, bn4_b, fc_w, fc_b, out);
}

// Round 14
// 1003.539 us; speedup vs baseline: 1.0498x; 1.0498x over previous
//
#include <hip/hip_runtime.h>
#include <math.h>

#define Sv 21952
#define HWc 784
#define CNT 351232.0f
#define EPS 1e-5f
#define PV 27000              // 30^3 padded volume per image
#define PT (16 * PV)          // padded positions total

typedef short bf16x8 __attribute__((ext_vector_type(8)));
typedef float f32x4 __attribute__((ext_vector_type(4)));
typedef float f32x16 __attribute__((ext_vector_type(16)));
typedef unsigned short u16x8 __attribute__((ext_vector_type(8)));

__device__ __forceinline__ unsigned short f2bf(float f) {
    unsigned u = __float_as_uint(f);
    u = (u + 0x7FFFu + ((u >> 16) & 1u)) >> 16;
    return (unsigned short)u;
}
__device__ __forceinline__ float bf2f(unsigned short h) {
    return __uint_as_float(((unsigned)h) << 16);
}

// async global->LDS DMA, 16B per lane. LDS dest = wave-uniform base + lane*16.
__device__ __forceinline__ void async16(const unsigned short* g, unsigned short* l) {
    __builtin_amdgcn_global_load_lds(
        (const __attribute__((address_space(1))) unsigned int*)g,
        (__attribute__((address_space(3))) unsigned int*)l, 16, 0, 0);
}

// ---------------------------------------------- border-only zero of padded bufs
template<int C>
__global__ __launch_bounds__(256) void k_zborder(unsigned short* __restrict__ buf) {
    int idx = blockIdx.x * 256 + threadIdx.x;
    if (idx >= PT) return;
    int p = idx % PV;
    int z = p / 900, y = (p / 30) % 30, x = p % 30;
    if (z >= 1 && z <= 28 && y >= 1 && y <= 28 && x >= 1 && x <= 28) return;
    u16x8 zv = {0, 0, 0, 0, 0, 0, 0, 0};
    u16x8* dst = (u16x8*)(buf + (long)idx * C);
    #pragma unroll
    for (int q = 0; q < C / 8; q++) dst[q] = zv;
}

// ---------------------------------------------------------------- offsets conv
__global__ __launch_bounds__(256) void k_offsets(const float* __restrict__ x,
        const float* __restrict__ ow, const float* __restrict__ ob,
        float* __restrict__ out) {
    int idx = blockIdx.x * 256 + threadIdx.x;
    int n = idx / Sv, s = idx % Sv;
    int d = s / HWc, r = s % HWc, h = r / 28, w = r % 28;
    const float* xb = x + (long)n * Sv;
    float xv[27];
    #pragma unroll
    for (int dz = 0; dz < 3; dz++)
      #pragma unroll
      for (int dy = 0; dy < 3; dy++)
        #pragma unroll
        for (int dx = 0; dx < 3; dx++) {
            int zz = d + dz - 1, yy = h + dy - 1, xx = w + dx - 1;
            bool ok = (unsigned)zz < 28u && (unsigned)yy < 28u && (unsigned)xx < 28u;
            xv[dz * 9 + dy * 3 + dx] = ok ? xb[zz * HWc + yy * 28 + xx] : 0.f;
        }
    float* op = out + (long)n * 81 * Sv + s;
    for (int c = 0; c < 81; c++) {
        float acc = ob[c];
        #pragma unroll
        for (int k = 0; k < 27; k++) acc += xv[k] * ow[c * 27 + k];
        op[(long)c * Sv] = acc;
    }
}

// ---------------------------------------------------------------- deform conv
// Tap-split: 2 threads per position (512-thread blocks). Thread t takes even
// taps (14), t+256 odd taps (13) -> dependent-gather chain per thread halves
// (216->112 loads), TLP doubles. Partials combine via padded LDS [256][33]
// (33 breaks the stride-32 bank alias). One f32 reassociation per channel
// (even-sum + odd-sum) — error ~1e-6, under the bf16 rounding floor.
__device__ __forceinline__ float fetch_pad(const float* __restrict__ xb,
                                           int zq, int yq, int xq) {
    int z = zq - 1, y = yq - 1, xx = xq - 1;
    bool ok = (unsigned)z < 28u && (unsigned)y < 28u && (unsigned)xx < 28u;
    return ok ? xb[z * HWc + y * 28 + xx] : 0.f;
}

__global__ __launch_bounds__(512) void k_deform(const float* __restrict__ x,
        const float* __restrict__ off, const float* __restrict__ dw,
        unsigned short* __restrict__ h1p) {
    __shared__ float w_s[32 * 27];
    __shared__ float part[256][33];
    for (int i = threadIdx.x; i < 32 * 27; i += 512) w_s[i] = dw[i];
    __syncthreads();
    int half = threadIdx.x >> 8;          // 0: even taps, 1: odd taps
    int t = threadIdx.x & 255;
    int idx = blockIdx.x * 256 + t;
    int n = idx / Sv, s = idx % Sv;
    int d = s / HWc, r = s % HWc, h = r / 28, w = r % 28;
    const float* xb = x + (long)n * Sv;
    const float* ofb = off + (long)n * 81 * Sv + s;
    float v[14];
    #pragma unroll
    for (int kk = 0; kk < 14; kk++) {
        int k = kk * 2 + half;
        if (k >= 27) { v[kk] = 0.f; continue; }   // only kk=13,half=1
        int ki = k / 9, kj = (k / 3) % 3, kl = k % 3;
        float pd = (float)(d + ki) + ofb[(long)k * Sv];
        float ph = (float)(h + kj) + ofb[(long)(27 + k) * Sv];
        float pw = (float)(w + kl) + ofb[(long)(54 + k) * Sv];
        float q0d = floorf(pd), q0h = floorf(ph), q0w = floorf(pw);
        float pcd = fminf(fmaxf(pd, 0.f), 29.f);
        float pch = fminf(fmaxf(ph, 0.f), 29.f);
        float pcw = fminf(fmaxf(pw, 0.f), 29.f);
        float q0cd = fminf(fmaxf(q0d, 0.f), 29.f);
        float q0ch = fminf(fmaxf(q0h, 0.f), 29.f);
        float q0cw = fminf(fmaxf(q0w, 0.f), 29.f);
        float q1cd = fminf(fmaxf(q0d + 1.f, 0.f), 29.f);
        float q1ch = fminf(fmaxf(q0h + 1.f, 0.f), 29.f);
        float q1cw = fminf(fmaxf(q0w + 1.f, 0.f), 29.f);
        float wz[2] = {1.f + (q0cd - pcd), 1.f - (q1cd - pcd)};
        float wy[2] = {1.f + (q0ch - pch), 1.f - (q1ch - pch)};
        float wx[2] = {1.f + (q0cw - pcw), 1.f - (q1cw - pcw)};
        int qz[2] = {(int)q0cd, (int)q1cd};
        int qy[2] = {(int)q0ch, (int)q1ch};
        int qx[2] = {(int)q0cw, (int)q1cw};
        float val = 0.f;
        #pragma unroll
        for (int cz = 0; cz < 2; cz++)
          #pragma unroll
          for (int cy = 0; cy < 2; cy++)
            #pragma unroll
            for (int cx = 0; cx < 2; cx++)
                val += wz[cz] * wy[cy] * wx[cx] * fetch_pad(xb, qz[cz], qy[cy], qx[cx]);
        v[kk] = val;
    }
    float acc[32];
    #pragma unroll
    for (int o = 0; o < 32; o++) {
        float a = 0.f;
        #pragma unroll
        for (int kk = 0; kk < 14; kk++) {
            int k = kk * 2 + half;
            if (k < 27) a += v[kk] * w_s[o * 27 + k];
        }
        acc[o] = a;
    }
    if (half) {
        #pragma unroll
        for (int o = 0; o < 32; o++) part[t][o] = acc[o];
    }
    __syncthreads();
    if (!half) {
        unsigned pb = ((((unsigned)n * 30 + (d + 1)) * 30 + (h + 1)) * 30 + (w + 1)) * 32;
        unsigned short tmp[32];
        #pragma unroll
        for (int o = 0; o < 32; o++)
            tmp[o] = f2bf(fmaxf(acc[o] + part[t][o], 0.f));
        u16x8* dst = (u16x8*)(h1p + pb);
        #pragma unroll
        for (int q = 0; q < 4; q++) dst[q] = ((u16x8*)tmp)[q];
    }
}

// ------------------------------------------------- BN1 stats over padded h1p
template<int C>
__global__ __launch_bounds__(256) void k_stats_p(const unsigned short* __restrict__ buf,
        float* __restrict__ sums) {
    constexpr int G = C / 8;
    constexpr int P = 256 / G;
    int t = threadIdx.x;
    int oct = t % G, ps = t / G;
    float s1[8], s2[8];
    #pragma unroll
    for (int j = 0; j < 8; j++) { s1[j] = 0.f; s2[j] = 0.f; }
    for (int p = blockIdx.x * P + ps; p < PT; p += gridDim.x * P) {
        u16x8 v = *(const u16x8*)(buf + (long)p * C + oct * 8);
        #pragma unroll
        for (int j = 0; j < 8; j++) {
            float f = bf2f(v[j]);
            s1[j] += f; s2[j] += f * f;
        }
    }
    __shared__ float sh[2][C];
    if (t < C) { sh[0][t] = 0.f; sh[1][t] = 0.f; }
    __syncthreads();
    #pragma unroll
    for (int j = 0; j < 8; j++) {
        atomicAdd(&sh[0][oct * 8 + j], s1[j]);
        atomicAdd(&sh[1][oct * 8 + j], s2[j]);
    }
    __syncthreads();
    if (t < C) { atomicAdd(&sums[t], sh[0][t]); atomicAdd(&sums[C + t], sh[1][t]); }
}

__global__ void k_finalize(const float* __restrict__ sums, const float* __restrict__ g,
        const float* __restrict__ bb, float* __restrict__ aff, int C) {
    int c = threadIdx.x;
    if (c < C) {
        float mean = sums[c] * (1.f / CNT);
        float var = sums[C + c] * (1.f / CNT) - mean * mean;
        float a = g[c] * rsqrtf(var + EPS);
        aff[c] = a;
        aff[C + c] = bb[c] - mean * a;
    }
}

// ------------------- weight prep: B-fragment swizzle for 32x32x16 MFMA
template<int CI, int COT>
__global__ __launch_bounds__(256) void k_wfrag32(const float* __restrict__ w,
        const float* __restrict__ affa, unsigned short* __restrict__ wf) {
    constexpr int NT32 = COT / 32;
    constexpr int KC = CI / 32;
    int tid = blockIdx.x * 256 + threadIdx.x;
    int lane = tid & 63, rest = tid >> 6;
    int kh = rest & 1; rest >>= 1;
    int nt = rest % NT32; rest /= NT32;
    int kc = rest % KC;
    int tap = rest / KC;
    if (tap >= 27) return;
    int co = nt * 32 + (lane & 31);
    int hi = lane >> 5;
    unsigned short tmp[8];
    #pragma unroll
    for (int j = 0; j < 8; j++) {
        int ci = kc * 32 + kh * 16 + hi * 8 + j;
        tmp[j] = f2bf(w[((long)co * CI + ci) * 27 + tap] * affa[ci]);
    }
    long oidx = ((((long)kc * 27 + tap) * NT32 + nt) * 2 + kh) * 512 + lane * 8;
    *(u16x8*)(wf + oidx) = *(u16x8*)tmp;
}

// --------------------- border-bias table, stage 1: per-tap channel sums
template<int CI, int COT>
__global__ __launch_bounds__(256) void k_tapsum(const float* __restrict__ w,
        const float* __restrict__ affb, float* __restrict__ S) {
    __shared__ float acc[27];
    int co = blockIdx.x;
    int t = threadIdx.x;
    if (t < 27) acc[t] = 0.f;
    __syncthreads();
    const float* wr = w + (long)co * CI * 27;
    for (int idx = t; idx < CI * 27; idx += 256)
        atomicAdd(&acc[idx % 27], wr[idx] * affb[idx / 27]);
    __syncthreads();
    if (t < 27) S[t * COT + co] = acc[t];
}

// --------------------- border-bias table, stage 2: combine valid taps per class
template<int COT>
__global__ void k_btab2(const float* __restrict__ S, const float* __restrict__ bias,
        float* __restrict__ T) {
    int tid = blockIdx.x * 256 + threadIdx.x;
    if (tid >= 27 * COT) return;
    int co = tid % COT, cls = tid / COT;
    int xc = cls % 3, yc = (cls / 3) % 3, zc = cls / 9;
    float val = bias[co];
    #pragma unroll
    for (int t = 0; t < 27; t++) {
        int dx = t % 3, dy = (t / 3) % 3, dz = t / 9;
        bool ok = (zc == 1 || (zc == 0 && dz >= 1) || (zc == 2 && dz <= 1))
               && (yc == 1 || (yc == 0 && dy >= 1) || (yc == 2 && dy <= 1))
               && (xc == 1 || (xc == 0 && dx >= 1) || (xc == 2 && dx <= 1));
        if (ok) val += S[t * COT + co];
    }
    T[cls * COT + co] = val;
}

// ------------------------------------------------------ MFMA implicit-GEMM conv
template<int CI, int COT, int WN, bool PAD_OUT, int SMODE>
__global__ __launch_bounds__(WN * 128, 2) void k_conv_mfma(
        const unsigned short* __restrict__ in,
        const unsigned short* __restrict__ wfrag,
        const float* __restrict__ Ttab,
        unsigned short* __restrict__ out,
        float* __restrict__ sa, float* __restrict__ sb) {
    constexpr int KC = CI / 32;
    constexpr int NT32 = COT / 32;
    constexpr int NTW = NT32 / 2;         // nt tiles per wave (4 waves)
    constexpr int NT = WN * 128;
    constexpr int CP = 720;               // 4z * 6y * 30x halo positions
    constexpr int CUU = CP * 5;           // 3600 16B units (5/pos, stride-80)
    constexpr int NLOAD = (CUU + NT - 1) / NT;
    constexpr int LDSU = CUU + 48;        // pad for last partial wave
    __shared__ unsigned short lds[LDSU * 8];   // 58368 B
    __shared__ float shs[2][COT];

    int tid = threadIdx.x, wv = tid >> 6, lane = tid & 63;
    int lcol = lane & 31, hi = lane >> 5;
    int wv_m = wv & 1, wv_n = wv >> 1;
    if (tid < COT) { shs[0][tid] = 0.f; shs[1][tid] = 0.f; }

    // XCD swizzle: each XCD (bx%8) owns 2 images; grid 1568 = 8*196
    int bx = blockIdx.x;
    int xcd = bx & 7, loc = bx >> 3;
    int n = xcd * 2 + loc / 98;
    int rem = loc % 98;
    int z0 = (rem / 7) * 2;               // even z-tile base, 0..26
    int y0 = (rem % 7) * 4;
    const unsigned short* src = in + ((long)((n * 30 + z0) * 30 + y0) * 30) * CI;

    // per-lane A bases (bytes into lds). wave wv_m owns rows wv_m*128..+127.
    int baseA[4];
    #pragma unroll
    for (int mt = 0; mt < 4; mt++) {
        int x = lcol; if (x > 27) x = 27;         // clip lanes (rows masked at store)
        int pos = (wv_m * 6 + mt) * 30 + x;
        baseA[mt] = pos * 80 + hi * 16;
    }

    f32x16 acc[4][NTW];
    #pragma unroll
    for (int mt = 0; mt < 4; mt++)
        #pragma unroll
        for (int nt = 0; nt < NTW; nt++)
            #pragma unroll
            for (int e = 0; e < 16; e++) acc[mt][nt][e] = 0.f;

    for (int kc = 0; kc < KC; kc++) {
        if (kc) __syncthreads();                  // all waves done reading lds
        #pragma unroll
        for (int j = 0; j < NLOAD; j++) {
            int wb = j * NT + (wv << 6);          // wave-uniform dest base (16B units)
            if (wb < CUU) {
                int u = wb + lane;
                if (u >= CUU) u = CUU - 1;        // clamp source (dest in pad region)
                int p = u / 5, s = u - p * 5;     // 5 units per position
                int q = s & 3;                    // pad slot s==4 dups quad 0
                int zl = p / 180, r = p - zl * 180;
                int yl = r / 30, xl = r - yl * 30;
                int so = (zl * 900 + yl * 30 + xl) * CI + q * 8 + kc * 32;
                async16(src + so, lds + (wb << 3));
            }
        }
        __syncthreads();                          // vmcnt(0) drain -> chunk staged
        const unsigned short* pwk =
            wfrag + (long)(kc * 27) * NT32 * 1024 + (long)wv_n * (NTW * 1024)
                  + lane * 8;
        bf16x8 bc[NTW][2];
        #pragma unroll
        for (int nt = 0; nt < NTW; nt++)
            #pragma unroll
            for (int kh = 0; kh < 2; kh++)
                bc[nt][kh] = *(const bf16x8*)(pwk + nt * 1024 + kh * 512);
        #pragma unroll
        for (int tap = 0; tap < 27; tap++) {
            int td = (((tap / 9) * 6 + (tap % 9) / 3) * 30 + tap % 3) * 80;
            bf16x8 bn[NTW][2];
            if (tap < 26) {                       // prefetch next tap's B
                const unsigned short* pwn = pwk + (long)(tap + 1) * NT32 * 1024;
                #pragma unroll
                for (int nt = 0; nt < NTW; nt++)
                    #pragma unroll
                    for (int kh = 0; kh < 2; kh++)
                        bn[nt][kh] = *(const bf16x8*)(pwn + nt * 1024 + kh * 512);
            }
            bf16x8 a[2][4];
            #pragma unroll
            for (int kh = 0; kh < 2; kh++)
                #pragma unroll
                for (int mt = 0; mt < 4; mt++)
                    a[kh][mt] = *(const bf16x8*)((const char*)lds
                                 + baseA[mt] + td + kh * 32);
            #pragma unroll
            for (int kh = 0; kh < 2; kh++)
                #pragma unroll
                for (int mt = 0; mt < 4; mt++)
                    #pragma unroll
                    for (int nt = 0; nt < NTW; nt++)
                        acc[mt][nt] = __builtin_amdgcn_mfma_f32_32x32x16_bf16(
                            a[kh][mt], bc[nt][kh], acc[mt][nt], 0, 0, 0);
            if (tap < 26) {
                #pragma unroll
                for (int nt = 0; nt < NTW; nt++)
                    #pragma unroll
                    for (int kh = 0; kh < 2; kh++)
                        bc[nt][kh] = bn[nt][kh];
            }
        }
    }

    // ---- epilogue: C/D layout col=lane&31, row=(reg&3)+8*(reg>>2)+4*(lane>>5)
    int zz = z0 + wv_m;
    int zc = (zz == 0) ? 0 : ((zz == 27) ? 2 : 1);
    float s1a[NTW], s2a[NTW];
    #pragma unroll
    for (int nt = 0; nt < NTW; nt++) { s1a[nt] = 0.f; s2a[nt] = 0.f; }
    #pragma unroll
    for (int mt = 0; mt < 4; mt++) {
        int y = y0 + mt;
        int yc = (y == 0) ? 0 : ((y == 27) ? 2 : 1);
        #pragma unroll
        for (int reg = 0; reg < 16; reg++) {
            int x = (reg & 3) + 8 * (reg >> 2) + 4 * hi;
            if (x >= 28) continue;                // per-lane predicate (hi half)
            int xc = (x == 0) ? 0 : ((x == 27) ? 2 : 1);
            int cls = (zc * 3 + yc) * 3 + xc;
            long ob = 0;
            if constexpr (SMODE == 0) {
                if (PAD_OUT)
                    ob = ((long)((n * 30 + zz + 1) * 30 + y + 1) * 30 + x + 1) * COT;
                else
                    ob = ((long)n * Sv + zz * HWc + y * 28 + x) * COT;
            }
            #pragma unroll
            for (int nt = 0; nt < NTW; nt++) {
                int co = wv_n * (NTW * 32) + nt * 32 + lcol;
                float v = acc[mt][nt][reg] + Ttab[cls * COT + co];
                unsigned short hb = f2bf(fmaxf(v, 0.f));
                if constexpr (SMODE == 0) out[ob + co] = hb;
                float vr = bf2f(hb);
                s1a[nt] += vr;
                s2a[nt] += vr * vr;
            }
        }
    }
    #pragma unroll
    for (int nt = 0; nt < NTW; nt++) {
        int co = wv_n * (NTW * 32) + nt * 32 + lcol;
        atomicAdd(&shs[0][co], s1a[nt]);
        atomicAdd(&shs[1][co], s2a[nt]);
    }
    __syncthreads();
    if (tid < COT) {
        if constexpr (SMODE == 1) {
            atomicAdd(&sa[n * COT + tid], shs[0][tid]);
        } else {
            atomicAdd(&sa[tid], shs[0][tid]);
        }
        atomicAdd(&sb[tid], shs[1][tid]);
    }
}

// -------------------------------------------------------------------- head
__global__ __launch_bounds__(256) void k_head(const float* __restrict__ pooled,
        const float* __restrict__ chsq, const float* __restrict__ g4,
        const float* __restrict__ b4, const float* __restrict__ fcw,
        const float* __restrict__ fcb, float* __restrict__ out) {
    __shared__ float feat[16 * 128];
    __shared__ float lg[160];
    __shared__ float corr[16];
    int t = threadIdx.x;
    if (t < 128) {
        float sum = 0.f;
        for (int n = 0; n < 16; n++) sum += pooled[n * 128 + t];
        float mean = sum * (1.f / CNT);
        float var = chsq[t] * (1.f / CNT) - mean * mean;
        float a = g4[t] * rsqrtf(var + EPS);
        float bb = b4[t] - mean * a;
        for (int n = 0; n < 16; n++)
            feat[n * 128 + t] = a * (pooled[n * 128 + t] * (1.f / (float)Sv)) + bb;
    }
    __syncthreads();
    if (t < 160) {
        int n = t / 10, j = t % 10;
        float acc = fcb[j];
        for (int c = 0; c < 128; c++) acc += feat[n * 128 + c] * fcw[j * 128 + c];
        lg[t] = acc;
    }
    __syncthreads();
    if (t < 16) {
        float mx = -1e30f;
        for (int j = 0; j < 10; j++) mx = fmaxf(mx, lg[t * 10 + j]);
        float se = 0.f;
        for (int j = 0; j < 10; j++) se += expf(lg[t * 10 + j] - mx);
        corr[t] = mx + logf(se);
    }
    __syncthreads();
    if (t < 160) out[t] = lg[t] - corr[t / 10];
}

// -------------------------------------------------------------------- launch
#define OFF_H3P 0L
#define OFF_H2P 110592000L
#define OFF_H1P 165888000L
#define OFF_WF2 200507392L
#define OFF_WF3 200617984L
#define OFF_WF4 201060352L
#define OFF_STATS 201945088L

extern "C" void kernel_launch(void* const* d_in, const int* in_sizes, int n_in,
                              void* d_out, int out_size, void* d_ws, size_t ws_size,
                              hipStream_t stream) {
    const float* x       = (const float*)d_in[0];
    const float* off_w   = (const float*)d_in[1];
    const float* off_b   = (const float*)d_in[2];
    const float* dconv_w = (const float*)d_in[3];
    const float* bn1_g   = (const float*)d_in[4];
    const float* bn1_b   = (const float*)d_in[5];
    const float* conv2_w = (const float*)d_in[6];
    const float* conv2_b = (const float*)d_in[7];
    const float* bn2_g   = (const float*)d_in[8];
    const float* bn2_b   = (const float*)d_in[9];
    const float* conv3_w = (const float*)d_in[10];
    const float* conv3_b = (const float*)d_in[11];
    const float* bn3_g   = (const float*)d_in[12];
    const float* bn3_b   = (const float*)d_in[13];
    const float* conv4_w = (const float*)d_in[14];
    const float* conv4_b = (const float*)d_in[15];
    const float* bn4_g   = (const float*)d_in[16];
    const float* bn4_b   = (const float*)d_in[17];
    const float* fc_w    = (const float*)d_in[18];
    const float* fc_b    = (const float*)d_in[19];

    float* out = (float*)d_out;
    float* offsets = out + 160;

    char* ws = (char*)d_ws;
    unsigned short* h3p = (unsigned short*)(ws + OFF_H3P);
    unsigned short* h2p = (unsigned short*)(ws + OFF_H2P);
    unsigned short* h1p = (unsigned short*)(ws + OFF_H1P);
    unsigned short* wf2 = (unsigned short*)(ws + OFF_WF2);
    unsigned short* wf3 = (unsigned short*)(ws + OFF_WF3);
    unsigned short* wf4 = (unsigned short*)(ws + OFF_WF4);
    float* st = (float*)(ws + OFF_STATS);
    float* sums1 = st;        float* aff1 = st + 64;
    float* sums2 = st + 128;  float* aff2 = st + 256;
    float* sums3 = st + 384;  float* aff3 = st + 640;
    float* chsq4 = st + 896;  float* pooled = st + 1024;
    float* T2 = st + 4096;    float* T3 = st + 8192;   float* T4 = st + 16384;
    float* Sb = st + 20480;   // 27*COT per-tap sums scratch (<= 3456 floats)

    hipMemsetAsync(st, 0, 3072 * sizeof(float), stream);
    k_zborder<32><<<dim3(1688), 256, 0, stream>>>(h1p);
    k_zborder<64><<<dim3(1688), 256, 0, stream>>>(h2p);
    k_zborder<128><<<dim3(1688), 256, 0, stream>>>(h3p);

    k_offsets<<<dim3(1372), 256, 0, stream>>>(x, off_w, off_b, offsets);
    k_deform<<<dim3(1372), 512, 0, stream>>>(x, offsets, dconv_w, h1p);

    k_stats_p<32><<<dim3(432), 256, 0, stream>>>(h1p, sums1);
    k_finalize<<<1, 32, 0, stream>>>(sums1, bn1_g, bn1_b, aff1, 32);
    k_wfrag32<32, 64><<<dim3(27), 256, 0, stream>>>(conv2_w, aff1, wf2);
    k_tapsum<32, 64><<<dim3(64), 256, 0, stream>>>(conv2_w, aff1 + 32, Sb);
    k_btab2<64><<<dim3(7), 256, 0, stream>>>(Sb, conv2_b, T2);
    k_conv_mfma<32, 64, 2, true, 0><<<dim3(1568), 256, 0, stream>>>(
        h1p, wf2, T2, h2p, sums2, sums2 + 64);

    k_finalize<<<1, 64, 0, stream>>>(sums2, bn2_g, bn2_b, aff2, 64);
    k_wfrag32<64, 128><<<dim3(108), 256, 0, stream>>>(conv3_w, aff2, wf3);
    k_tapsum<64, 128><<<dim3(128), 256, 0, stream>>>(conv3_w, aff2 + 64, Sb);
    k_btab2<128><<<dim3(14), 256, 0, stream>>>(Sb, conv3_b, T3);
    k_conv_mfma<64, 128, 2, true, 0><<<dim3(1568), 256, 0, stream>>>(
        h2p, wf3, T3, h3p, sums3, sums3 + 128);

    k_finalize<<<1, 128, 0, stream>>>(sums3, bn3_g, bn3_b, aff3, 128);
    k_wfrag32<128, 128><<<dim3(216), 256, 0, stream>>>(conv4_w, aff3, wf4);
    k_tapsum<128, 128><<<dim3(128), 256, 0, stream>>>(conv4_w, aff3 + 128, Sb);
    k_btab2<128><<<dim3(14), 256, 0, stream>>>(Sb, conv4_b, T4);
    k_conv_mfma<128, 128, 2, false, 1><<<dim3(1568), 256, 0, stream>>>(
        h3p, wf4, T4, (unsigned short*)0, pooled, chsq4);

    k_head<<<1, 256, 0, stream>>>(pooled, chsq4, bn4_g, bn4_b, fc_w, fc_b, out);
}

// Round 15
// 921.762 us; speedup vs baseline: 1.1430x; 1.0887x over previous
//
#include <hip/hip_runtime.h>
#include <math.h>

#define Sv 21952
#define HWc 784
#define CNT 351232.0f
#define EPS 1e-5f
#define PV 27000              // 30^3 padded volume per image
#define PT (16 * PV)          // padded positions total

typedef short bf16x8 __attribute__((ext_vector_type(8)));
typedef float f32x4 __attribute__((ext_vector_type(4)));
typedef float f32x16 __attribute__((ext_vector_type(16)));
typedef unsigned short u16x8 __attribute__((ext_vector_type(8)));

__device__ __forceinline__ unsigned short f2bf(float f) {
    unsigned u = __float_as_uint(f);
    u = (u + 0x7FFFu + ((u >> 16) & 1u)) >> 16;
    return (unsigned short)u;
}
__device__ __forceinline__ float bf2f(unsigned short h) {
    return __uint_as_float(((unsigned)h) << 16);
}

// async global->LDS DMA, 16B per lane. LDS dest = wave-uniform base + lane*16.
__device__ __forceinline__ void async16(const unsigned short* g, unsigned short* l) {
    __builtin_amdgcn_global_load_lds(
        (const __attribute__((address_space(1))) unsigned int*)g,
        (__attribute__((address_space(3))) unsigned int*)l, 16, 0, 0);
}

// ---------------------------------------------- border-only zero of padded bufs
template<int C>
__global__ __launch_bounds__(256) void k_zborder(unsigned short* __restrict__ buf) {
    int idx = blockIdx.x * 256 + threadIdx.x;
    if (idx >= PT) return;
    int p = idx % PV;
    int z = p / 900, y = (p / 30) % 30, x = p % 30;
    if (z >= 1 && z <= 28 && y >= 1 && y <= 28 && x >= 1 && x <= 28) return;
    u16x8 zv = {0, 0, 0, 0, 0, 0, 0, 0};
    u16x8* dst = (u16x8*)(buf + (long)idx * C);
    #pragma unroll
    for (int q = 0; q < C / 8; q++) dst[q] = zv;
}

// ---------------------------------------------------------------- offsets conv
__global__ __launch_bounds__(256) void k_offsets(const float* __restrict__ x,
        const float* __restrict__ ow, const float* __restrict__ ob,
        float* __restrict__ out) {
    int idx = blockIdx.x * 256 + threadIdx.x;
    int n = idx / Sv, s = idx % Sv;
    int d = s / HWc, r = s % HWc, h = r / 28, w = r % 28;
    const float* xb = x + (long)n * Sv;
    float xv[27];
    #pragma unroll
    for (int dz = 0; dz < 3; dz++)
      #pragma unroll
      for (int dy = 0; dy < 3; dy++)
        #pragma unroll
        for (int dx = 0; dx < 3; dx++) {
            int zz = d + dz - 1, yy = h + dy - 1, xx = w + dx - 1;
            bool ok = (unsigned)zz < 28u && (unsigned)yy < 28u && (unsigned)xx < 28u;
            xv[dz * 9 + dy * 3 + dx] = ok ? xb[zz * HWc + yy * 28 + xx] : 0.f;
        }
    float* op = out + (long)n * 81 * Sv + s;
    for (int c = 0; c < 81; c++) {
        float acc = ob[c];
        #pragma unroll
        for (int k = 0; k < 27; k++) acc += xv[k] * ow[c * 27 + k];
        op[(long)c * Sv] = acc;
    }
}

// ---------------------------------------------------------------- deform conv
// 4-way tap-split: 4 threads per position (256-thread blocks, 64 pos/block).
// Thread group half=0..3 takes taps k = kk*4+half -> dependent-gather chain
// 56 loads/thread (was 112 at 2-way, 216 unsplit). Partials combine via LDS
// part[3][64][36]: stride 36 floats = 144B (16B-aligned -> f32x4 moves;
// (4t+o) bank walk is conflict-free for b128). ~31KB LDS -> ~5 blocks/CU.
__device__ __forceinline__ float fetch_pad(const float* __restrict__ xb,
                                           int zq, int yq, int xq) {
    int z = zq - 1, y = yq - 1, xx = xq - 1;
    bool ok = (unsigned)z < 28u && (unsigned)y < 28u && (unsigned)xx < 28u;
    return ok ? xb[z * HWc + y * 28 + xx] : 0.f;
}

__global__ __launch_bounds__(256) void k_deform(const float* __restrict__ x,
        const float* __restrict__ off, const float* __restrict__ dw,
        unsigned short* __restrict__ h1p) {
    __shared__ float w_s[32 * 27];
    __shared__ float part[3][64][36];
    for (int i = threadIdx.x; i < 32 * 27; i += 256) w_s[i] = dw[i];
    __syncthreads();
    int half = threadIdx.x >> 6;          // 0..3: tap subset
    int t = threadIdx.x & 63;             // position within block
    int idx = blockIdx.x * 64 + t;
    int n = idx / Sv, s = idx % Sv;
    int d = s / HWc, r = s % HWc, h = r / 28, w = r % 28;
    const float* xb = x + (long)n * Sv;
    const float* ofb = off + (long)n * 81 * Sv + s;
    float v[7];
    #pragma unroll
    for (int kk = 0; kk < 7; kk++) {
        int k = kk * 4 + half;
        if (k >= 27) { v[kk] = 0.f; continue; }   // only kk=6,half=3
        int ki = k / 9, kj = (k / 3) % 3, kl = k % 3;
        float pd = (float)(d + ki) + ofb[(long)k * Sv];
        float ph = (float)(h + kj) + ofb[(long)(27 + k) * Sv];
        float pw = (float)(w + kl) + ofb[(long)(54 + k) * Sv];
        float q0d = floorf(pd), q0h = floorf(ph), q0w = floorf(pw);
        float pcd = fminf(fmaxf(pd, 0.f), 29.f);
        float pch = fminf(fmaxf(ph, 0.f), 29.f);
        float pcw = fminf(fmaxf(pw, 0.f), 29.f);
        float q0cd = fminf(fmaxf(q0d, 0.f), 29.f);
        float q0ch = fminf(fmaxf(q0h, 0.f), 29.f);
        float q0cw = fminf(fmaxf(q0w, 0.f), 29.f);
        float q1cd = fminf(fmaxf(q0d + 1.f, 0.f), 29.f);
        float q1ch = fminf(fmaxf(q0h + 1.f, 0.f), 29.f);
        float q1cw = fminf(fmaxf(q0w + 1.f, 0.f), 29.f);
        float wz[2] = {1.f + (q0cd - pcd), 1.f - (q1cd - pcd)};
        float wy[2] = {1.f + (q0ch - pch), 1.f - (q1ch - pch)};
        float wx[2] = {1.f + (q0cw - pcw), 1.f - (q1cw - pcw)};
        int qz[2] = {(int)q0cd, (int)q1cd};
        int qy[2] = {(int)q0ch, (int)q1ch};
        int qx[2] = {(int)q0cw, (int)q1cw};
        float val = 0.f;
        #pragma unroll
        for (int cz = 0; cz < 2; cz++)
          #pragma unroll
          for (int cy = 0; cy < 2; cy++)
            #pragma unroll
            for (int cx = 0; cx < 2; cx++)
                val += wz[cz] * wy[cy] * wx[cx] * fetch_pad(xb, qz[cz], qy[cy], qx[cx]);
        v[kk] = val;
    }
    float acc[32];
    #pragma unroll
    for (int o = 0; o < 32; o++) {
        float a = 0.f;
        #pragma unroll
        for (int kk = 0; kk < 7; kk++) {
            int k = kk * 4 + half;
            if (k < 27) a += v[kk] * w_s[o * 27 + k];
        }
        acc[o] = a;
    }
    if (half) {
        f32x4* dstp = (f32x4*)part[half - 1][t];
        #pragma unroll
        for (int j = 0; j < 8; j++) dstp[j] = ((f32x4*)acc)[j];
    }
    __syncthreads();
    if (!half) {
        unsigned pb = ((((unsigned)n * 30 + (d + 1)) * 30 + (h + 1)) * 30 + (w + 1)) * 32;
        unsigned short tmp[32];
        #pragma unroll
        for (int j = 0; j < 8; j++) {
            f32x4 p0 = ((f32x4*)part[0][t])[j];
            f32x4 p1 = ((f32x4*)part[1][t])[j];
            f32x4 p2 = ((f32x4*)part[2][t])[j];
            #pragma unroll
            for (int e = 0; e < 4; e++) {
                int o = j * 4 + e;
                tmp[o] = f2bf(fmaxf(acc[o] + p0[e] + p1[e] + p2[e], 0.f));
            }
        }
        u16x8* dst = (u16x8*)(h1p + pb);
        #pragma unroll
        for (int q = 0; q < 4; q++) dst[q] = ((u16x8*)tmp)[q];
    }
}

// ------------------------------------------------- BN1 stats over padded h1p
template<int C>
__global__ __launch_bounds__(256) void k_stats_p(const unsigned short* __restrict__ buf,
        float* __restrict__ sums) {
    constexpr int G = C / 8;
    constexpr int P = 256 / G;
    int t = threadIdx.x;
    int oct = t % G, ps = t / G;
    float s1[8], s2[8];
    #pragma unroll
    for (int j = 0; j < 8; j++) { s1[j] = 0.f; s2[j] = 0.f; }
    for (int p = blockIdx.x * P + ps; p < PT; p += gridDim.x * P) {
        u16x8 v = *(const u16x8*)(buf + (long)p * C + oct * 8);
        #pragma unroll
        for (int j = 0; j < 8; j++) {
            float f = bf2f(v[j]);
            s1[j] += f; s2[j] += f * f;
        }
    }
    __shared__ float sh[2][C];
    if (t < C) { sh[0][t] = 0.f; sh[1][t] = 0.f; }
    __syncthreads();
    #pragma unroll
    for (int j = 0; j < 8; j++) {
        atomicAdd(&sh[0][oct * 8 + j], s1[j]);
        atomicAdd(&sh[1][oct * 8 + j], s2[j]);
    }
    __syncthreads();
    if (t < C) { atomicAdd(&sums[t], sh[0][t]); atomicAdd(&sums[C + t], sh[1][t]); }
}

__global__ void k_finalize(const float* __restrict__ sums, const float* __restrict__ g,
        const float* __restrict__ bb, float* __restrict__ aff, int C) {
    int c = threadIdx.x;
    if (c < C) {
        float mean = sums[c] * (1.f / CNT);
        float var = sums[C + c] * (1.f / CNT) - mean * mean;
        float a = g[c] * rsqrtf(var + EPS);
        aff[c] = a;
        aff[C + c] = bb[c] - mean * a;
    }
}

// ------------------- weight prep: B-fragment swizzle for 32x32x16 MFMA
template<int CI, int COT>
__global__ __launch_bounds__(256) void k_wfrag32(const float* __restrict__ w,
        const float* __restrict__ affa, unsigned short* __restrict__ wf) {
    constexpr int NT32 = COT / 32;
    constexpr int KC = CI / 32;
    int tid = blockIdx.x * 256 + threadIdx.x;
    int lane = tid & 63, rest = tid >> 6;
    int kh = rest & 1; rest >>= 1;
    int nt = rest % NT32; rest /= NT32;
    int kc = rest % KC;
    int tap = rest / KC;
    if (tap >= 27) return;
    int co = nt * 32 + (lane & 31);
    int hi = lane >> 5;
    unsigned short tmp[8];
    #pragma unroll
    for (int j = 0; j < 8; j++) {
        int ci = kc * 32 + kh * 16 + hi * 8 + j;
        tmp[j] = f2bf(w[((long)co * CI + ci) * 27 + tap] * affa[ci]);
    }
    long oidx = ((((long)kc * 27 + tap) * NT32 + nt) * 2 + kh) * 512 + lane * 8;
    *(u16x8*)(wf + oidx) = *(u16x8*)tmp;
}

// --------------------- border-bias table, stage 1: per-tap channel sums
template<int CI, int COT>
__global__ __launch_bounds__(256) void k_tapsum(const float* __restrict__ w,
        const float* __restrict__ affb, float* __restrict__ S) {
    __shared__ float acc[27];
    int co = blockIdx.x;
    int t = threadIdx.x;
    if (t < 27) acc[t] = 0.f;
    __syncthreads();
    const float* wr = w + (long)co * CI * 27;
    for (int idx = t; idx < CI * 27; idx += 256)
        atomicAdd(&acc[idx % 27], wr[idx] * affb[idx / 27]);
    __syncthreads();
    if (t < 27) S[t * COT + co] = acc[t];
}

// --------------------- border-bias table, stage 2: combine valid taps per class
template<int COT>
__global__ void k_btab2(const float* __restrict__ S, const float* __restrict__ bias,
        float* __restrict__ T) {
    int tid = blockIdx.x * 256 + threadIdx.x;
    if (tid >= 27 * COT) return;
    int co = tid % COT, cls = tid / COT;
    int xc = cls % 3, yc = (cls / 3) % 3, zc = cls / 9;
    float val = bias[co];
    #pragma unroll
    for (int t = 0; t < 27; t++) {
        int dx = t % 3, dy = (t / 3) % 3, dz = t / 9;
        bool ok = (zc == 1 || (zc == 0 && dz >= 1) || (zc == 2 && dz <= 1))
               && (yc == 1 || (yc == 0 && dy >= 1) || (yc == 2 && dy <= 1))
               && (xc == 1 || (xc == 0 && dx >= 1) || (xc == 2 && dx <= 1));
        if (ok) val += S[t * COT + co];
    }
    T[cls * COT + co] = val;
}

// ------------------------------------------------------ MFMA implicit-GEMM conv
template<int CI, int COT, int WN, bool PAD_OUT, int SMODE>
__global__ __launch_bounds__(WN * 128, 2) void k_conv_mfma(
        const unsigned short* __restrict__ in,
        const unsigned short* __restrict__ wfrag,
        const float* __restrict__ Ttab,
        unsigned short* __restrict__ out,
        float* __restrict__ sa, float* __restrict__ sb) {
    constexpr int KC = CI / 32;
    constexpr int NT32 = COT / 32;
    constexpr int NTW = NT32 / 2;         // nt tiles per wave (4 waves)
    constexpr int NT = WN * 128;
    constexpr int CP = 720;               // 4z * 6y * 30x halo positions
    constexpr int CUU = CP * 5;           // 3600 16B units (5/pos, stride-80)
    constexpr int NLOAD = (CUU + NT - 1) / NT;
    constexpr int LDSU = CUU + 48;        // pad for last partial wave
    __shared__ unsigned short lds[LDSU * 8];   // 58368 B
    __shared__ float shs[2][COT];

    int tid = threadIdx.x, wv = tid >> 6, lane = tid & 63;
    int lcol = lane & 31, hi = lane >> 5;
    int wv_m = wv & 1, wv_n = wv >> 1;
    if (tid < COT) { shs[0][tid] = 0.f; shs[1][tid] = 0.f; }

    // XCD swizzle: each XCD (bx%8) owns 2 images; grid 1568 = 8*196
    int bx = blockIdx.x;
    int xcd = bx & 7, loc = bx >> 3;
    int n = xcd * 2 + loc / 98;
    int rem = loc % 98;
    int z0 = (rem / 7) * 2;               // even z-tile base, 0..26
    int y0 = (rem % 7) * 4;
    const unsigned short* src = in + ((long)((n * 30 + z0) * 30 + y0) * 30) * CI;

    // per-lane A bases (bytes into lds). wave wv_m owns rows wv_m*128..+127.
    int baseA[4];
    #pragma unroll
    for (int mt = 0; mt < 4; mt++) {
        int x = lcol; if (x > 27) x = 27;         // clip lanes (rows masked at store)
        int pos = (wv_m * 6 + mt) * 30 + x;
        baseA[mt] = pos * 80 + hi * 16;
    }

    f32x16 acc[4][NTW];
    #pragma unroll
    for (int mt = 0; mt < 4; mt++)
        #pragma unroll
        for (int nt = 0; nt < NTW; nt++)
            #pragma unroll
            for (int e = 0; e < 16; e++) acc[mt][nt][e] = 0.f;

    for (int kc = 0; kc < KC; kc++) {
        if (kc) __syncthreads();                  // all waves done reading lds
        #pragma unroll
        for (int j = 0; j < NLOAD; j++) {
            int wb = j * NT + (wv << 6);          // wave-uniform dest base (16B units)
            if (wb < CUU) {
                int u = wb + lane;
                if (u >= CUU) u = CUU - 1;        // clamp source (dest in pad region)
                int p = u / 5, s = u - p * 5;     // 5 units per position
                int q = s & 3;                    // pad slot s==4 dups quad 0
                int zl = p / 180, r = p - zl * 180;
                int yl = r / 30, xl = r - yl * 30;
                int so = (zl * 900 + yl * 30 + xl) * CI + q * 8 + kc * 32;
                async16(src + so, lds + (wb << 3));
            }
        }
        __syncthreads();                          // vmcnt(0) drain -> chunk staged
        const unsigned short* pwk =
            wfrag + (long)(kc * 27) * NT32 * 1024 + (long)wv_n * (NTW * 1024)
                  + lane * 8;
        bf16x8 bc[NTW][2];
        #pragma unroll
        for (int nt = 0; nt < NTW; nt++)
            #pragma unroll
            for (int kh = 0; kh < 2; kh++)
                bc[nt][kh] = *(const bf16x8*)(pwk + nt * 1024 + kh * 512);
        #pragma unroll
        for (int tap = 0; tap < 27; tap++) {
            int td = (((tap / 9) * 6 + (tap % 9) / 3) * 30 + tap % 3) * 80;
            bf16x8 bn[NTW][2];
            if (tap < 26) {                       // prefetch next tap's B
                const unsigned short* pwn = pwk + (long)(tap + 1) * NT32 * 1024;
                #pragma unroll
                for (int nt = 0; nt < NTW; nt++)
                    #pragma unroll
                    for (int kh = 0; kh < 2; kh++)
                        bn[nt][kh] = *(const bf16x8*)(pwn + nt * 1024 + kh * 512);
            }
            bf16x8 a[2][4];
            #pragma unroll
            for (int kh = 0; kh < 2; kh++)
                #pragma unroll
                for (int mt = 0; mt < 4; mt++)
                    a[kh][mt] = *(const bf16x8*)((const char*)lds
                                 + baseA[mt] + td + kh * 32);
            #pragma unroll
            for (int kh = 0; kh < 2; kh++)
                #pragma unroll
                for (int mt = 0; mt < 4; mt++)
                    #pragma unroll
                    for (int nt = 0; nt < NTW; nt++)
                        acc[mt][nt] = __builtin_amdgcn_mfma_f32_32x32x16_bf16(
                            a[kh][mt], bc[nt][kh], acc[mt][nt], 0, 0, 0);
            if (tap < 26) {
                #pragma unroll
                for (int nt = 0; nt < NTW; nt++)
                    #pragma unroll
                    for (int kh = 0; kh < 2; kh++)
                        bc[nt][kh] = bn[nt][kh];
            }
        }
    }

    // ---- epilogue: C/D layout col=lane&31, row=(reg&3)+8*(reg>>2)+4*(lane>>5)
    int zz = z0 + wv_m;
    int zc = (zz == 0) ? 0 : ((zz == 27) ? 2 : 1);
    float s1a[NTW], s2a[NTW];
    #pragma unroll
    for (int nt = 0; nt < NTW; nt++) { s1a[nt] = 0.f; s2a[nt] = 0.f; }
    #pragma unroll
    for (int mt = 0; mt < 4; mt++) {
        int y = y0 + mt;
        int yc = (y == 0) ? 0 : ((y == 27) ? 2 : 1);
        #pragma unroll
        for (int reg = 0; reg < 16; reg++) {
            int x = (reg & 3) + 8 * (reg >> 2) + 4 * hi;
            if (x >= 28) continue;                // per-lane predicate (hi half)
            int xc = (x == 0) ? 0 : ((x == 27) ? 2 : 1);
            int cls = (zc * 3 + yc) * 3 + xc;
            long ob = 0;
            if constexpr (SMODE == 0) {
                if (PAD_OUT)
                    ob = ((long)((n * 30 + zz + 1) * 30 + y + 1) * 30 + x + 1) * COT;
                else
                    ob = ((long)n * Sv + zz * HWc + y * 28 + x) * COT;
            }
            #pragma unroll
            for (int nt = 0; nt < NTW; nt++) {
                int co = wv_n * (NTW * 32) + nt * 32 + lcol;
                float v = acc[mt][nt][reg] + Ttab[cls * COT + co];
                unsigned short hb = f2bf(fmaxf(v, 0.f));
                if constexpr (SMODE == 0) out[ob + co] = hb;
                float vr = bf2f(hb);
                s1a[nt] += vr;
                s2a[nt] += vr * vr;
            }
        }
    }
    #pragma unroll
    for (int nt = 0; nt < NTW; nt++) {
        int co = wv_n * (NTW * 32) + nt * 32 + lcol;
        atomicAdd(&shs[0][co], s1a[nt]);
        atomicAdd(&shs[1][co], s2a[nt]);
    }
    __syncthreads();
    if (tid < COT) {
        if constexpr (SMODE == 1) {
            atomicAdd(&sa[n * COT + tid], shs[0][tid]);
        } else {
            atomicAdd(&sa[tid], shs[0][tid]);
        }
        atomicAdd(&sb[tid], shs[1][tid]);
    }
}

// -------------------------------------------------------------------- head
__global__ __launch_bounds__(256) void k_head(const float* __restrict__ pooled,
        const float* __restrict__ chsq, const float* __restrict__ g4,
        const float* __restrict__ b4, const float* __restrict__ fcw,
        const float* __restrict__ fcb, float* __restrict__ out) {
    __shared__ float feat[16 * 128];
    __shared__ float lg[160];
    __shared__ float corr[16];
    int t = threadIdx.x;
    if (t < 128) {
        float sum = 0.f;
        for (int n = 0; n < 16; n++) sum += pooled[n * 128 + t];
        float mean = sum * (1.f / CNT);
        float var = chsq[t] * (1.f / CNT) - mean * mean;
        float a = g4[t] * rsqrtf(var + EPS);
        float bb = b4[t] - mean * a;
        for (int n = 0; n < 16; n++)
            feat[n * 128 + t] = a * (pooled[n * 128 + t] * (1.f / (float)Sv)) + bb;
    }
    __syncthreads();
    if (t < 160) {
        int n = t / 10, j = t % 10;
        float acc = fcb[j];
        for (int c = 0; c < 128; c++) acc += feat[n * 128 + c] * fcw[j * 128 + c];
        lg[t] = acc;
    }
    __syncthreads();
    if (t < 16) {
        float mx = -1e30f;
        for (int j = 0; j < 10; j++) mx = fmaxf(mx, lg[t * 10 + j]);
        float se = 0.f;
        for (int j = 0; j < 10; j++) se += expf(lg[t * 10 + j] - mx);
        corr[t] = mx + logf(se);
    }
    __syncthreads();
    if (t < 160) out[t] = lg[t] - corr[t / 10];
}

// -------------------------------------------------------------------- launch
#define OFF_H3P 0L
#define OFF_H2P 110592000L
#define OFF_H1P 165888000L
#define OFF_WF2 200507392L
#define OFF_WF3 200617984L
#define OFF_WF4 201060352L
#define OFF_STATS 201945088L

extern "C" void kernel_launch(void* const* d_in, const int* in_sizes, int n_in,
                              void* d_out, int out_size, void* d_ws, size_t ws_size,
                              hipStream_t stream) {
    const float* x       = (const float*)d_in[0];
    const float* off_w   = (const float*)d_in[1];
    const float* off_b   = (const float*)d_in[2];
    const float* dconv_w = (const float*)d_in[3];
    const float* bn1_g   = (const float*)d_in[4];
    const float* bn1_b   = (const float*)d_in[5];
    const float* conv2_w = (const float*)d_in[6];
    const float* conv2_b = (const float*)d_in[7];
    const float* bn2_g   = (const float*)d_in[8];
    const float* bn2_b   = (const float*)d_in[9];
    const float* conv3_w = (const float*)d_in[10];
    const float* conv3_b = (const float*)d_in[11];
    const float* bn3_g   = (const float*)d_in[12];
    const float* bn3_b   = (const float*)d_in[13];
    const float* conv4_w = (const float*)d_in[14];
    const float* conv4_b = (const float*)d_in[15];
    const float* bn4_g   = (const float*)d_in[16];
    const float* bn4_b   = (const float*)d_in[17];
    const float* fc_w    = (const float*)d_in[18];
    const float* fc_b    = (const float*)d_in[19];

    float* out = (float*)d_out;
    float* offsets = out + 160;

    char* ws = (char*)d_ws;
    unsigned short* h3p = (unsigned short*)(ws + OFF_H3P);
    unsigned short* h2p = (unsigned short*)(ws + OFF_H2P);
    unsigned short* h1p = (unsigned short*)(ws + OFF_H1P);
    unsigned short* wf2 = (unsigned short*)(ws + OFF_WF2);
    unsigned short* wf3 = (unsigned short*)(ws + OFF_WF3);
    unsigned short* wf4 = (unsigned short*)(ws + OFF_WF4);
    float* st = (float*)(ws + OFF_STATS);
    float* sums1 = st;        float* aff1 = st + 64;
    float* sums2 = st + 128;  float* aff2 = st + 256;
    float* sums3 = st + 384;  float* aff3 = st + 640;
    float* chsq4 = st + 896;  float* pooled = st + 1024;
    float* T2 = st + 4096;    float* T3 = st + 8192;   float* T4 = st + 16384;
    float* Sb = st + 20480;   // 27*COT per-tap sums scratch (<= 3456 floats)

    hipMemsetAsync(st, 0, 3072 * sizeof(float), stream);
    k_zborder<32><<<dim3(1688), 256, 0, stream>>>(h1p);
    k_zborder<64><<<dim3(1688), 256, 0, stream>>>(h2p);
    k_zborder<128><<<dim3(1688), 256, 0, stream>>>(h3p);

    k_offsets<<<dim3(1372), 256, 0, stream>>>(x, off_w, off_b, offsets);
    k_deform<<<dim3(5488), 256, 0, stream>>>(x, offsets, dconv_w, h1p);

    k_stats_p<32><<<dim3(432), 256, 0, stream>>>(h1p, sums1);
    k_finalize<<<1, 32, 0, stream>>>(sums1, bn1_g, bn1_b, aff1, 32);
    k_wfrag32<32, 64><<<dim3(27), 256, 0, stream>>>(conv2_w, aff1, wf2);
    k_tapsum<32, 64><<<dim3(64), 256, 0, stream>>>(conv2_w, aff1 + 32, Sb);
    k_btab2<64><<<dim3(7), 256, 0, stream>>>(Sb, conv2_b, T2);
    k_conv_mfma<32, 64, 2, true, 0><<<dim3(1568), 256, 0, stream>>>(
        h1p, wf2, T2, h2p, sums2, sums2 + 64);

    k_finalize<<<1, 64, 0, stream>>>(sums2, bn2_g, bn2_b, aff2, 64);
    k_wfrag32<64, 128><<<dim3(108), 256, 0, stream>>>(conv3_w, aff2, wf3);
    k_tapsum<64, 128><<<dim3(128), 256, 0, stream>>>(conv3_w, aff2 + 64, Sb);
    k_btab2<128><<<dim3(14), 256, 0, stream>>>(Sb, conv3_b, T3);
    k_conv_mfma<64, 128, 2, true, 0><<<dim3(1568), 256, 0, stream>>>(
        h2p, wf3, T3, h3p, sums3, sums3 + 128);

    k_finalize<<<1, 128, 0, stream>>>(sums3, bn3_g, bn3_b, aff3, 128);
    k_wfrag32<128, 128><<<dim3(216), 256, 0, stream>>>(conv4_w, aff3, wf4);
    k_tapsum<128, 128><<<dim3(128), 256, 0, stream>>>(conv4_w, aff3 + 128, Sb);
    k_btab2<128><<<dim3(14), 256, 0, stream>>>(Sb, conv4_b, T4);
    k_conv_mfma<128, 128, 2, false, 1><<<dim3(1568), 256, 0, stream>>>(
        h3p, wf4, T4, (unsigned short*)0, pooled, chsq4);

    k_head<<<1, 256, 0, stream>>>(pooled, chsq4, bn4_g, bn4_b, fc_w, fc_b, out);
}